// Round 5
// baseline (366.588 us; speedup 1.0000x reference)
//
#include <hip/hip_runtime.h>

// Quadratic positional encoding, fused:
//   out = (E0@Wr + br) * (E@Wg + bg) + (E*E)@Wb + bb,  E = 36-dim trig encoding
// N=1e6 points, OUT=256. Output 1.02 GB f32 -> store-BW bound (~155us at 6.7TB/s).
// R5: replace __syncthreads (vmcnt(0) drain!) with lgkmcnt-only raw barriers so
// nontemporal output stores stay in flight across tiles; prefetch next tile's
// inputs during the rt0 store pass. All cross-wave hazards here are LDS-only.

typedef short bf16x8 __attribute__((ext_vector_type(8)));
typedef short bf16x4 __attribute__((ext_vector_type(4)));
typedef float f32x16 __attribute__((ext_vector_type(16)));
typedef float f32x4  __attribute__((ext_vector_type(4)));

__device__ __forceinline__ unsigned short f2bf(float x) {
  unsigned int u = __float_as_uint(x);
  return (unsigned short)((u + 0x7FFFu + ((u >> 16) & 1u)) >> 16);  // RNE
}

// a in radians; v_sin/v_cos take revolutions, reduce with fract first
__device__ __forceinline__ void fsincos(float a, float* s, float* c) {
  float r = a * 0.15915494309189535f;
  r = r - floorf(r);
  *s = __builtin_amdgcn_sinf(r);
  *c = __builtin_amdgcn_cosf(r);
}

// Barrier that only drains LDS ops: global stores keep flying. All inter-wave
// dependencies in the tile loop are through LDS (enc/outt/xyl), never global.
__device__ __forceinline__ void bar_lgkm() {
  asm volatile("s_waitcnt lgkmcnt(0)" ::: "memory");
  __builtin_amdgcn_s_barrier();
  asm volatile("" ::: "memory");
}

// Reordered K layout (k'):
//   k' 0..31  : freq f = k'>>2, comp {sin px, cos px, sin py, cos py} (orig k = k'+4)
//   k' 32..35 : header {x, y, sin base, cos base} (orig k = k'-32); rows 32,33 zeroed in B
//   k' 36..47 : zero pad
__global__ __launch_bounds__(256, 2) void qpe_kernel(
    const float* __restrict__ X, const float* __restrict__ Y,
    const float* __restrict__ V, const float* __restrict__ V0,
    const float* __restrict__ Wr, const float* __restrict__ Wg,
    const float* __restrict__ Wb, const float* __restrict__ Br,
    const float* __restrict__ Bg, const float* __restrict__ Bb,
    float* __restrict__ Out, int nt)
{
  __shared__ __align__(16) unsigned short enc[3][64][64];  // 24.5 KB, rows 128B, XOR-swizzled
  __shared__ float4 xyl[64];                               // f32 sideband {x,y,x2,y2}
  __shared__ __align__(16) float outt[32][256];            // 32 KB output staging (one rt tile)

  const int tid  = threadIdx.x;
  const int lane = tid & 63;
  const int wid  = tid >> 6;   // wave 0..3 -> col block wid*64
  const int hi   = lane >> 5;  // 0/1
  const int ln   = lane & 31;

  // ---- zero entire enc LDS once: keeps k'=36..47 pad zero forever ----
  {
    bf16x8 z = {0,0,0,0,0,0,0,0};
    bf16x8* pz = (bf16x8*)(&enc[0][0][0]);
#pragma unroll
    for (int i = 0; i < 6; ++i) pz[tid + 256 * i] = z;
  }

  // ---- resident B fragments (3 mats x 3 K-steps x 2 col-tiles) + sideband ----
  bf16x8 Bf[2][3][3];
  float  wc[2][6];   // Wr[0],Wr[1],Wg[0],Wg[1],Wb[0],Wb[1] at this col
  float  bs[2][3];   // br, bg, bb at this col
  {
    const float* const Wm[3] = {Wr, Wg, Wb};
#pragma unroll
    for (int ct = 0; ct < 2; ++ct) {
      int col = wid * 64 + ct * 32 + ln;
#pragma unroll
      for (int m = 0; m < 3; ++m) {
#pragma unroll
        for (int s = 0; s < 3; ++s) {
          bf16x8 f;
#pragma unroll
          for (int j = 0; j < 8; ++j) {
            int kp = s * 16 + hi * 8 + j;
            float val = 0.0f;
            if (kp < 32) val = Wm[m][(kp + 4) * 256 + col];
            else if (kp == 34 || kp == 35) val = Wm[m][(kp - 32) * 256 + col];
            f[j] = (short)f2bf(val);
          }
          Bf[ct][m][s] = f;
        }
      }
      wc[ct][0] = Wr[col];       wc[ct][1] = Wr[256 + col];
      wc[ct][2] = Wg[col];       wc[ct][3] = Wg[256 + col];
      wc[ct][4] = Wb[col];       wc[ct][5] = Wb[256 + col];
      bs[ct][0] = Br[col];       bs[ct][1] = Bg[col];       bs[ct][2] = Bb[col];
    }
  }
  __syncthreads();

  const float TPF = 62.831853071795864f;  // 2*pi*10
  const int   pl = tid >> 2;              // point-local 0..63
  const int   qq = tid & 3;               // freq pair: f = 2q, 2q+1
  const float scA = __int_as_float((124 + 2 * qq) << 23);  // 2^(2q-3)
  const float scB = scA + scA;

  // input prefetch registers (consumed at top of tile, refilled mid-tile)
  size_t pt0 = (size_t)blockIdx.x * 64 + pl;
  float xx = X[pt0], yy = Y[pt0], vv = V[pt0], v0v = V0[pt0];

  for (int t = blockIdx.x; t < nt; t += gridDim.x) {
    // ======== E phase: 64 points x 4 threads each (inputs already in regs) ====
    {
      float wn  = TPF / vv;
      float wn0 = TPF / v0v;
      float xw0 = xx * wn0, yw0 = yy * wn0, xw = xx * wn, yw = yy * wn;
      bf16x8 e0, e1, e2;
      float s, c;
      fsincos(xw0 * scA, &s, &c); e0[0] = (short)f2bf(s); e0[1] = (short)f2bf(c);
      fsincos(yw0 * scA, &s, &c); e0[2] = (short)f2bf(s); e0[3] = (short)f2bf(c);
      fsincos(xw0 * scB, &s, &c); e0[4] = (short)f2bf(s); e0[5] = (short)f2bf(c);
      fsincos(yw0 * scB, &s, &c); e0[6] = (short)f2bf(s); e0[7] = (short)f2bf(c);
      fsincos(xw * scA, &s, &c);  e1[0] = (short)f2bf(s); e1[1] = (short)f2bf(c);
                                  e2[0] = (short)f2bf(s * s); e2[1] = (short)f2bf(c * c);
      fsincos(yw * scA, &s, &c);  e1[2] = (short)f2bf(s); e1[3] = (short)f2bf(c);
                                  e2[2] = (short)f2bf(s * s); e2[3] = (short)f2bf(c * c);
      fsincos(xw * scB, &s, &c);  e1[4] = (short)f2bf(s); e1[5] = (short)f2bf(c);
                                  e2[4] = (short)f2bf(s * s); e2[5] = (short)f2bf(c * c);
      fsincos(yw * scB, &s, &c);  e1[6] = (short)f2bf(s); e1[7] = (short)f2bf(c);
                                  e2[6] = (short)f2bf(s * s); e2[7] = (short)f2bf(c * c);
      int swz = (pl & 7) << 4;
      *(bf16x8*)((char*)&enc[0][pl][0] + ((16 * qq) ^ swz)) = e0;
      *(bf16x8*)((char*)&enc[1][pl][0] + ((16 * qq) ^ swz)) = e1;
      *(bf16x8*)((char*)&enc[2][pl][0] + ((16 * qq) ^ swz)) = e2;
      if (qq == 0) {
        float s0, c0, s1, c1;
        fsincos(xw0 * 0.0625f, &s0, &c0);
        fsincos(xw  * 0.0625f, &s1, &c1);
        bf16x4 h0, h1, h2;
        h0[0] = (short)f2bf(xx); h0[1] = (short)f2bf(yy);
        h0[2] = (short)f2bf(s0); h0[3] = (short)f2bf(c0);
        h1[0] = (short)f2bf(xx); h1[1] = (short)f2bf(yy);
        h1[2] = (short)f2bf(s1); h1[3] = (short)f2bf(c1);
        h2[0] = (short)f2bf(xx * xx); h2[1] = (short)f2bf(yy * yy);
        h2[2] = (short)f2bf(s1 * s1); h2[3] = (short)f2bf(c1 * c1);
        *(bf16x4*)((char*)&enc[0][pl][0] + (64 ^ swz)) = h0;
        *(bf16x4*)((char*)&enc[1][pl][0] + (64 ^ swz)) = h1;
        *(bf16x4*)((char*)&enc[2][pl][0] + (64 ^ swz)) = h2;
        xyl[pl] = make_float4(xx, yy, xx * xx, yy * yy);
      }
    }
    bar_lgkm();  // enc/xyl ready; prev tile's store-pass reads of outt long done

    // ======== M phase: 2 row-tiles, each staged through LDS then row-stored ====
#pragma unroll
    for (int rt = 0; rt < 2; ++rt) {
      bf16x8 Af[3][3];
      int p = rt * 32 + ln;
      int swz2 = (p & 7) << 4;
#pragma unroll
      for (int m = 0; m < 3; ++m)
#pragma unroll
        for (int s = 0; s < 3; ++s)
          Af[m][s] = *(const bf16x8*)((const char*)&enc[m][p][0] +
                                      ((s * 32 + hi * 16) ^ swz2));

      if (rt == 1) bar_lgkm();  // rt0 store pass done reading outt

#pragma unroll
      for (int ct = 0; ct < 2; ++ct) {
        f32x16 ar, ag, aq;
#pragma unroll
        for (int i = 0; i < 16; ++i) { ar[i] = 0.f; ag[i] = 0.f; aq[i] = 0.f; }
#pragma unroll
        for (int s = 0; s < 3; ++s) {
          ar = __builtin_amdgcn_mfma_f32_32x32x16_bf16(Af[0][s], Bf[ct][0][s], ar, 0, 0, 0);
          ag = __builtin_amdgcn_mfma_f32_32x32x16_bf16(Af[1][s], Bf[ct][1][s], ag, 0, 0, 0);
          aq = __builtin_amdgcn_mfma_f32_32x32x16_bf16(Af[2][s], Bf[ct][2][s], aq, 0, 0, 0);
        }
        int col = wid * 64 + ct * 32 + ln;
#pragma unroll
        for (int i = 0; i < 16; ++i) {
          int rl = (i & 3) + 8 * (i >> 2) + 4 * hi;   // row within 32-tile
          float4 xy = xyl[rt * 32 + rl];
          float rr = ar[i] + xy.x * wc[ct][0] + xy.y * wc[ct][1] + bs[ct][0];
          float gg = ag[i] + xy.x * wc[ct][2] + xy.y * wc[ct][3] + bs[ct][1];
          float qv = aq[i] + xy.z * wc[ct][4] + xy.w * wc[ct][5] + bs[ct][2];
          outt[rl][col] = rr * gg + qv;   // bank = col%32 = ln -> conflict-free
        }
      }
      bar_lgkm();  // outt tile complete

      // store pass: one full 1KB output row per wave-instruction (stays in flight)
      {
        const float* src = &outt[0][0];
        size_t base = (size_t)(t * 64 + rt * 32) * 256;
#pragma unroll
        for (int it = 0; it < 8; ++it) {
          int idx = it * 1024 + tid * 4;   // f32 index; wave covers one full row
          f32x4 v = *(const f32x4*)(src + idx);
          __builtin_nontemporal_store(v, (f32x4*)(Out + base + idx));
        }
      }

      if (rt == 0) {
        // prefetch next tile's inputs while rt0 stores fly
        int tn = t + (int)gridDim.x;
        size_t ptn = (size_t)(tn < nt ? tn : t) * 64 + pl;
        xx = X[ptn]; yy = Y[ptn]; vv = V[ptn]; v0v = V0[ptn];
      }
    }
    bar_lgkm();  // protect enc/xyl before next E phase overwrite
  }
}

extern "C" void kernel_launch(void* const* d_in, const int* in_sizes, int n_in,
                              void* d_out, int out_size, void* d_ws, size_t ws_size,
                              hipStream_t stream) {
  const float* X  = (const float*)d_in[0];
  const float* Y  = (const float*)d_in[1];
  const float* V  = (const float*)d_in[2];
  const float* V0 = (const float*)d_in[3];
  const float* Wr = (const float*)d_in[4];
  const float* Wg = (const float*)d_in[5];
  const float* Wb = (const float*)d_in[6];
  const float* Br = (const float*)d_in[7];
  const float* Bg = (const float*)d_in[8];
  const float* Bb = (const float*)d_in[9];
  float* Out = (float*)d_out;
  int n  = in_sizes[0];
  int nt = n >> 6;  // N=1e6 is divisible by 64
  // grid 512 = exactly 2 resident blocks/CU (58KB LDS): stable pipelining,
  // each block grid-strides ~30 tiles so stores overlap next tile's compute.
  qpe_kernel<<<dim3(512), dim3(256), 0, stream>>>(X, Y, V, V0, Wr, Wg, Wb,
                                                  Br, Bg, Bb, Out, nt);
}

// Round 6
// 218.496 us; speedup vs baseline: 1.6778x; 1.6778x over previous
//
#include <hip/hip_runtime.h>

// Quadratic positional encoding, fused:
//   out = (E0@Wr + br) * (E@Wg + bg) + (E*E)@Wb + bb,  E = 36-dim trig encoding
// N=1e6 points, OUT=256. Output 1.02 GB f32 -> store-BW bound (~155us at 6.7TB/s).
// R6: occupancy attack. 512-thread blocks (8 waves), same 64-pt tile & 58KB LDS
// -> 16 waves/CU (4/SIMD, was 2/SIMD). E phase: 1 freq/thread (4 fsincos).
// M phase: 32 cols/wave. v_cvt_pk_bf16_f32 replaces bit-twiddled f2bf.

typedef short bf16x8 __attribute__((ext_vector_type(8)));
typedef float f32x16 __attribute__((ext_vector_type(16)));
typedef float f32x4  __attribute__((ext_vector_type(4)));
typedef unsigned int u32x2 __attribute__((ext_vector_type(2)));

__device__ __forceinline__ unsigned short f2bf(float x) {  // setup only
  unsigned int u = __float_as_uint(x);
  return (unsigned short)((u + 0x7FFFu + ((u >> 16) & 1u)) >> 16);  // RNE
}

// pack 2 f32 -> 2 bf16 (RNE) in one instruction
__device__ __forceinline__ unsigned int cvtpk(float lo, float hi) {
  unsigned int r;
  asm("v_cvt_pk_bf16_f32 %0, %1, %2" : "=v"(r) : "v"(lo), "v"(hi));
  return r;
}

// a in radians; v_sin/v_cos take revolutions, reduce with fract first
__device__ __forceinline__ void fsincos(float a, float* s, float* c) {
  float r = a * 0.15915494309189535f;
  r = r - floorf(r);
  *s = __builtin_amdgcn_sinf(r);
  *c = __builtin_amdgcn_cosf(r);
}

// Barrier that only drains LDS ops: global (nt) stores keep flying. All
// inter-wave dependencies in the tile loop are through LDS (enc/outt/xyl).
__device__ __forceinline__ void bar_lgkm() {
  asm volatile("s_waitcnt lgkmcnt(0)" ::: "memory");
  __builtin_amdgcn_s_barrier();
  asm volatile("" ::: "memory");
}

// Reordered K layout (k'):
//   k' 0..31  : freq f = k'>>2, comp {sin px, cos px, sin py, cos py} (orig k = k'+4)
//   k' 32..35 : header {x, y, sin base, cos base} (orig k = k'-32); rows 32,33 zeroed in B
//   k' 36..47 : zero pad
__global__ __launch_bounds__(512, 4) void qpe_kernel(
    const float* __restrict__ X, const float* __restrict__ Y,
    const float* __restrict__ V, const float* __restrict__ V0,
    const float* __restrict__ Wr, const float* __restrict__ Wg,
    const float* __restrict__ Wb, const float* __restrict__ Br,
    const float* __restrict__ Bg, const float* __restrict__ Bb,
    float* __restrict__ Out, int nt)
{
  __shared__ __align__(16) unsigned short enc[3][64][64];  // 24.5 KB, rows 128B, XOR-swizzled
  __shared__ float4 xyl[64];                               // f32 sideband {x,y,x2,y2}
  __shared__ __align__(16) float outt[32][256];            // 32 KB output staging (one rt tile)

  const int tid  = threadIdx.x;
  const int lane = tid & 63;
  const int wid  = tid >> 6;   // wave 0..7 -> col block wid*32
  const int hi   = lane >> 5;  // 0/1
  const int ln   = lane & 31;

  // ---- zero entire enc LDS once: keeps k'=36..47 pad zero forever ----
  {
    bf16x8 z = {0,0,0,0,0,0,0,0};
    bf16x8* pz = (bf16x8*)(&enc[0][0][0]);
#pragma unroll
    for (int i = 0; i < 3; ++i) pz[tid + 512 * i] = z;
  }

  // ---- resident B fragments (3 mats x 3 K-steps, 32 cols/wave) + sideband ----
  bf16x8 Bf[3][3];
  float  wc[6];   // Wr[0],Wr[1],Wg[0],Wg[1],Wb[0],Wb[1] at this col
  float  bs[3];   // br, bg, bb at this col
  {
    const float* const Wm[3] = {Wr, Wg, Wb};
    int col = wid * 32 + ln;
#pragma unroll
    for (int m = 0; m < 3; ++m) {
#pragma unroll
      for (int s = 0; s < 3; ++s) {
        bf16x8 f;
#pragma unroll
        for (int j = 0; j < 8; ++j) {
          int kp = s * 16 + hi * 8 + j;
          float val = 0.0f;
          if (kp < 32) val = Wm[m][(kp + 4) * 256 + col];
          else if (kp == 34 || kp == 35) val = Wm[m][(kp - 32) * 256 + col];
          f[j] = (short)f2bf(val);
        }
        Bf[m][s] = f;
      }
    }
    wc[0] = Wr[col];  wc[1] = Wr[256 + col];
    wc[2] = Wg[col];  wc[3] = Wg[256 + col];
    wc[4] = Wb[col];  wc[5] = Wb[256 + col];
    bs[0] = Br[col];  bs[1] = Bg[col];  bs[2] = Bb[col];
  }
  __syncthreads();

  const float TPF = 62.831853071795864f;  // 2*pi*10
  const int   pl = tid >> 3;              // point-local 0..63
  const int   qq = tid & 7;               // freq 0..7
  const float sc = __int_as_float((124 + qq) << 23);  // 2^(qq-3)

  // input prefetch registers (consumed at top of tile, refilled mid-tile)
  size_t pt0 = (size_t)blockIdx.x * 64 + pl;
  float xx = X[pt0], yy = Y[pt0], vv = V[pt0], v0v = V0[pt0];

  for (int t = blockIdx.x; t < nt; t += gridDim.x) {
    // ======== E phase: 64 points x 8 threads (1 freq each) ========
    {
      float wn  = TPF / vv;
      float wn0 = TPF / v0v;
      float xw0 = xx * wn0, yw0 = yy * wn0, xw = xx * wn, yw = yy * wn;
      float sx0, cx0, sy0, cy0, sx, cx, sy, cy;
      fsincos(xw0 * sc, &sx0, &cx0);
      fsincos(yw0 * sc, &sy0, &cy0);
      fsincos(xw  * sc, &sx,  &cx);
      fsincos(yw  * sc, &sy,  &cy);
      int swz = (pl & 7) << 4;
      int off = (8 * qq) ^ swz;
      u32x2 w0; w0[0] = cvtpk(sx0, cx0);       w0[1] = cvtpk(sy0, cy0);
      u32x2 w1; w1[0] = cvtpk(sx, cx);         w1[1] = cvtpk(sy, cy);
      u32x2 w2; w2[0] = cvtpk(sx * sx, cx * cx); w2[1] = cvtpk(sy * sy, cy * cy);
      *(u32x2*)((char*)&enc[0][pl][0] + off) = w0;
      *(u32x2*)((char*)&enc[1][pl][0] + off) = w1;
      *(u32x2*)((char*)&enc[2][pl][0] + off) = w2;
      if (qq == 0) {
        float s0, c0, s1, c1;
        fsincos(xw0 * 0.0625f, &s0, &c0);
        fsincos(xw  * 0.0625f, &s1, &c1);
        u32x2 h0; h0[0] = cvtpk(xx, yy);           h0[1] = cvtpk(s0, c0);
        u32x2 h1; h1[0] = cvtpk(xx, yy);           h1[1] = cvtpk(s1, c1);
        u32x2 h2; h2[0] = cvtpk(xx * xx, yy * yy); h2[1] = cvtpk(s1 * s1, c1 * c1);
        int hoff = 64 ^ swz;
        *(u32x2*)((char*)&enc[0][pl][0] + hoff) = h0;
        *(u32x2*)((char*)&enc[1][pl][0] + hoff) = h1;
        *(u32x2*)((char*)&enc[2][pl][0] + hoff) = h2;
        xyl[pl] = make_float4(xx, yy, xx * xx, yy * yy);
      }
    }
    bar_lgkm();  // enc/xyl ready

    // ======== M phase: 2 row-tiles, each staged through LDS then row-stored ====
#pragma unroll
    for (int rt = 0; rt < 2; ++rt) {
      bf16x8 Af[3][3];
      int p = rt * 32 + ln;
      int swz2 = (p & 7) << 4;
#pragma unroll
      for (int m = 0; m < 3; ++m)
#pragma unroll
        for (int s = 0; s < 3; ++s)
          Af[m][s] = *(const bf16x8*)((const char*)&enc[m][p][0] +
                                      ((s * 32 + hi * 16) ^ swz2));

      if (rt == 1) bar_lgkm();  // rt0 store pass done reading outt

      f32x16 ar, ag, aq;
#pragma unroll
      for (int i = 0; i < 16; ++i) { ar[i] = 0.f; ag[i] = 0.f; aq[i] = 0.f; }
#pragma unroll
      for (int s = 0; s < 3; ++s) {
        ar = __builtin_amdgcn_mfma_f32_32x32x16_bf16(Af[0][s], Bf[0][s], ar, 0, 0, 0);
        ag = __builtin_amdgcn_mfma_f32_32x32x16_bf16(Af[1][s], Bf[1][s], ag, 0, 0, 0);
        aq = __builtin_amdgcn_mfma_f32_32x32x16_bf16(Af[2][s], Bf[2][s], aq, 0, 0, 0);
      }
      int col = wid * 32 + ln;
#pragma unroll
      for (int i = 0; i < 16; ++i) {
        int rl = (i & 3) + 8 * (i >> 2) + 4 * hi;   // row within 32-tile
        float4 xy = xyl[rt * 32 + rl];
        float rr = ar[i] + xy.x * wc[0] + xy.y * wc[1] + bs[0];
        float gg = ag[i] + xy.x * wc[2] + xy.y * wc[3] + bs[1];
        float qv = aq[i] + xy.z * wc[4] + xy.w * wc[5] + bs[2];
        outt[rl][col] = rr * gg + qv;   // bank = col%32 = ln -> conflict-free
      }
      bar_lgkm();  // outt tile complete

      // store pass: one full 1KB output row per wave-instruction (stays in flight)
      {
        const float* src = &outt[0][0];
        size_t base = (size_t)(t * 64 + rt * 32) * 256;
#pragma unroll
        for (int it = 0; it < 4; ++it) {
          int idx = it * 2048 + tid * 4;   // f32 index; each wave covers one full row
          f32x4 v = *(const f32x4*)(src + idx);
          __builtin_nontemporal_store(v, (f32x4*)(Out + base + idx));
        }
      }

      if (rt == 0) {
        // prefetch next tile's inputs while rt0 stores fly
        int tn = t + (int)gridDim.x;
        size_t ptn = (size_t)(tn < nt ? tn : t) * 64 + pl;
        xx = X[ptn]; yy = Y[ptn]; vv = V[ptn]; v0v = V0[ptn];
      }
    }
    bar_lgkm();  // protect enc/xyl before next E phase overwrite
  }
}

extern "C" void kernel_launch(void* const* d_in, const int* in_sizes, int n_in,
                              void* d_out, int out_size, void* d_ws, size_t ws_size,
                              hipStream_t stream) {
  const float* X  = (const float*)d_in[0];
  const float* Y  = (const float*)d_in[1];
  const float* V  = (const float*)d_in[2];
  const float* V0 = (const float*)d_in[3];
  const float* Wr = (const float*)d_in[4];
  const float* Wg = (const float*)d_in[5];
  const float* Wb = (const float*)d_in[6];
  const float* Br = (const float*)d_in[7];
  const float* Bg = (const float*)d_in[8];
  const float* Bb = (const float*)d_in[9];
  float* Out = (float*)d_out;
  int n  = in_sizes[0];
  int nt = n >> 6;  // N=1e6 is divisible by 64
  // 512 blocks x 512 threads = exactly 2 resident blocks/CU (58KB LDS),
  // 16 waves/CU = 4 waves/SIMD.
  qpe_kernel<<<dim3(512), dim3(512), 0, stream>>>(X, Y, V, V0, Wr, Wg, Wb,
                                                  Br, Bg, Bb, Out, nt);
}

// Round 7
// 218.083 us; speedup vs baseline: 1.6810x; 1.0019x over previous
//
#include <hip/hip_runtime.h>

// Quadratic positional encoding, fused:
//   out = (E0@Wr + br) * (E@Wg + bg) + (E*E)@Wb + bb,  E = 36-dim trig encoding
// N=1e6 points, OUT=256. Output 1.02 GB f32 -> store-BW bound (~155us at 6.8TB/s).
// R7: everything into the bf16 GEMM. x,y and x^2,y^2 rows now bf16 (precision
// budget re-audited: adds <=0.01 absmax, threshold 0.065); biases become a
// constant-1.0 K-row (k'=36) so the epilogue is a single fma per output:
//   out = ar*ag + aq.  xyl sideband deleted. 4 barriers/tile (was 5), rt1's
// MFMA overlaps rt0's store-pass drain.

typedef short bf16x8 __attribute__((ext_vector_type(8)));
typedef float f32x16 __attribute__((ext_vector_type(16)));
typedef float f32x4  __attribute__((ext_vector_type(4)));
typedef unsigned int u32x2 __attribute__((ext_vector_type(2)));

__device__ __forceinline__ unsigned short f2bf(float x) {  // setup only
  unsigned int u = __float_as_uint(x);
  return (unsigned short)((u + 0x7FFFu + ((u >> 16) & 1u)) >> 16);  // RNE
}

// pack 2 f32 -> 2 bf16 (RNE) in one instruction
__device__ __forceinline__ unsigned int cvtpk(float lo, float hi) {
  unsigned int r;
  asm("v_cvt_pk_bf16_f32 %0, %1, %2" : "=v"(r) : "v"(lo), "v"(hi));
  return r;
}

// a in radians; v_sin/v_cos take revolutions, reduce with fract first
__device__ __forceinline__ void fsincos(float a, float* s, float* c) {
  float r = a * 0.15915494309189535f;
  r = r - floorf(r);
  *s = __builtin_amdgcn_sinf(r);
  *c = __builtin_amdgcn_cosf(r);
}

// Barrier that only drains LDS ops: global (nt) stores keep flying. All
// inter-wave dependencies in the tile loop are through LDS (enc/outt).
__device__ __forceinline__ void bar_lgkm() {
  asm volatile("s_waitcnt lgkmcnt(0)" ::: "memory");
  __builtin_amdgcn_s_barrier();
  asm volatile("" ::: "memory");
}

// Reordered K layout (k'):
//   k' 0..31  : freq f = k'>>2, comp {sin px, cos px, sin py, cos py} (orig k = k'+4)
//   k' 32..35 : header {x, y, sin base, cos base} (orig k = 0..3)
//   k' 36     : constant 1.0; B row 36 = bias  -> epilogue is one fma
//   k' 37..47 : zero pad
__global__ __launch_bounds__(512, 4) void qpe_kernel(
    const float* __restrict__ X, const float* __restrict__ Y,
    const float* __restrict__ V, const float* __restrict__ V0,
    const float* __restrict__ Wr, const float* __restrict__ Wg,
    const float* __restrict__ Wb, const float* __restrict__ Br,
    const float* __restrict__ Bg, const float* __restrict__ Bb,
    float* __restrict__ Out, int nt)
{
  __shared__ __align__(16) unsigned short enc[3][64][64];  // 24.5 KB, rows 128B, XOR-swizzled
  __shared__ __align__(16) float outt[32][256];            // 32 KB output staging (one rt tile)

  const int tid  = threadIdx.x;
  const int lane = tid & 63;
  const int wid  = tid >> 6;   // wave 0..7 -> col block wid*32
  const int hi   = lane >> 5;  // 0/1
  const int ln   = lane & 31;

  // ---- zero entire enc LDS once (pad rows stay zero forever) ----
  {
    bf16x8 z = {0,0,0,0,0,0,0,0};
    bf16x8* pz = (bf16x8*)(&enc[0][0][0]);
#pragma unroll
    for (int i = 0; i < 3; ++i) pz[tid + 512 * i] = z;
  }
  __syncthreads();
  // ---- k'=36 constant-1.0 row (swizzled address, set once) ----
  if (tid < 192) {
    int m = tid >> 6, p = tid & 63;
    int swz = (p & 7) << 4;
    // chunk 4 (k'32..39) lives at byte (64^swz); k'36,37 are its bytes 8..11
    *(unsigned int*)((char*)&enc[m][p][0] + ((64 ^ swz) + 8)) = 0x00003F80u;  // {1.0bf, 0}
  }

  // ---- resident B fragments (3 mats x 3 K-steps, 32 cols/wave) ----
  bf16x8 Bf[3][3];
  {
    const float* const Wm[3] = {Wr, Wg, Wb};
    const float* const Bs[3] = {Br, Bg, Bb};
    int col = wid * 32 + ln;
#pragma unroll
    for (int m = 0; m < 3; ++m) {
#pragma unroll
      for (int s = 0; s < 3; ++s) {
        bf16x8 f;
#pragma unroll
        for (int j = 0; j < 8; ++j) {
          int kp = s * 16 + hi * 8 + j;
          float val = 0.0f;
          if (kp < 32)       val = Wm[m][(kp + 4) * 256 + col];  // freq rows
          else if (kp < 36)  val = Wm[m][(kp - 32) * 256 + col]; // x,y,sinb,cosb
          else if (kp == 36) val = Bs[m][col];                   // bias row
          f[j] = (short)f2bf(val);
        }
        Bf[m][s] = f;
      }
    }
  }
  __syncthreads();

  const float TPF = 62.831853071795864f;  // 2*pi*10
  const int   pl = tid >> 3;              // point-local 0..63
  const int   qq = tid & 7;               // freq 0..7
  const float sc = __int_as_float((124 + qq) << 23);  // 2^(qq-3)

  // input prefetch registers (consumed at top of tile, refilled mid-tile)
  size_t pt0 = (size_t)blockIdx.x * 64 + pl;
  float xx = X[pt0], yy = Y[pt0], vv = V[pt0], v0v = V0[pt0];

  for (int t = blockIdx.x; t < nt; t += gridDim.x) {
    // ======== E phase: 64 points x 8 threads (1 freq each) ========
    {
      float wn  = TPF / vv;
      float wn0 = TPF / v0v;
      float xw0 = xx * wn0, yw0 = yy * wn0, xw = xx * wn, yw = yy * wn;
      float sx0, cx0, sy0, cy0, sx, cx, sy, cy;
      fsincos(xw0 * sc, &sx0, &cx0);
      fsincos(yw0 * sc, &sy0, &cy0);
      fsincos(xw  * sc, &sx,  &cx);
      fsincos(yw  * sc, &sy,  &cy);
      int swz = (pl & 7) << 4;
      int off = (8 * qq) ^ swz;
      u32x2 w0; w0[0] = cvtpk(sx0, cx0);         w0[1] = cvtpk(sy0, cy0);
      u32x2 w1; w1[0] = cvtpk(sx, cx);           w1[1] = cvtpk(sy, cy);
      u32x2 w2; w2[0] = cvtpk(sx * sx, cx * cx); w2[1] = cvtpk(sy * sy, cy * cy);
      *(u32x2*)((char*)&enc[0][pl][0] + off) = w0;
      *(u32x2*)((char*)&enc[1][pl][0] + off) = w1;
      *(u32x2*)((char*)&enc[2][pl][0] + off) = w2;
      if (qq == 0) {
        float s0, c0, s1, c1;
        fsincos(xw0 * 0.0625f, &s0, &c0);
        fsincos(xw  * 0.0625f, &s1, &c1);
        u32x2 h0; h0[0] = cvtpk(xx, yy);           h0[1] = cvtpk(s0, c0);
        u32x2 h1; h1[0] = cvtpk(xx, yy);           h1[1] = cvtpk(s1, c1);
        u32x2 h2; h2[0] = cvtpk(xx * xx, yy * yy); h2[1] = cvtpk(s1 * s1, c1 * c1);
        int hoff = 64 ^ swz;   // chunk 4 bytes 0..7 = k'32..35
        *(u32x2*)((char*)&enc[0][pl][0] + hoff) = h0;
        *(u32x2*)((char*)&enc[1][pl][0] + hoff) = h1;
        *(u32x2*)((char*)&enc[2][pl][0] + hoff) = h2;
      }
    }
    bar_lgkm();  // barA: enc ready; prev-tile store1 reads of outt also pre-date this

    // ======== rt0: MFMA + 1-fma epilogue into outt ========
    const int col = wid * 32 + ln;
    {
      bf16x8 Af[3][3];
      int swz2 = (ln & 7) << 4;
#pragma unroll
      for (int m = 0; m < 3; ++m)
#pragma unroll
        for (int s = 0; s < 3; ++s)
          Af[m][s] = *(const bf16x8*)((const char*)&enc[m][ln][0] +
                                      ((s * 32 + hi * 16) ^ swz2));
      f32x16 ar, ag, aq;
#pragma unroll
      for (int i = 0; i < 16; ++i) { ar[i] = 0.f; ag[i] = 0.f; aq[i] = 0.f; }
#pragma unroll
      for (int s = 0; s < 3; ++s) {
        ar = __builtin_amdgcn_mfma_f32_32x32x16_bf16(Af[0][s], Bf[0][s], ar, 0, 0, 0);
        ag = __builtin_amdgcn_mfma_f32_32x32x16_bf16(Af[1][s], Bf[1][s], ag, 0, 0, 0);
        aq = __builtin_amdgcn_mfma_f32_32x32x16_bf16(Af[2][s], Bf[2][s], aq, 0, 0, 0);
      }
#pragma unroll
      for (int i = 0; i < 16; ++i) {
        int rl = (i & 3) + 8 * (i >> 2) + 4 * hi;
        outt[rl][col] = ar[i] * ag[i] + aq[i];
      }
    }
    bar_lgkm();  // barB: outt(rt0) complete

    // store pass rt0 (nt stores stay in flight) + rt1 A-loads/MFMA overlap
    {
      const float* src = &outt[0][0];
      size_t base = (size_t)(t * 64) * 256;
#pragma unroll
      for (int it = 0; it < 4; ++it) {
        int idx = it * 2048 + tid * 4;
        f32x4 v = *(const f32x4*)(src + idx);
        __builtin_nontemporal_store(v, (f32x4*)(Out + base + idx));
      }
    }
    {
      bf16x8 Af[3][3];
      int p = 32 + ln;
      int swz2 = (p & 7) << 4;
#pragma unroll
      for (int m = 0; m < 3; ++m)
#pragma unroll
        for (int s = 0; s < 3; ++s)
          Af[m][s] = *(const bf16x8*)((const char*)&enc[m][p][0] +
                                      ((s * 32 + hi * 16) ^ swz2));
      f32x16 ar, ag, aq;
#pragma unroll
      for (int i = 0; i < 16; ++i) { ar[i] = 0.f; ag[i] = 0.f; aq[i] = 0.f; }
#pragma unroll
      for (int s = 0; s < 3; ++s) {
        ar = __builtin_amdgcn_mfma_f32_32x32x16_bf16(Af[0][s], Bf[0][s], ar, 0, 0, 0);
        ag = __builtin_amdgcn_mfma_f32_32x32x16_bf16(Af[1][s], Bf[1][s], ag, 0, 0, 0);
        aq = __builtin_amdgcn_mfma_f32_32x32x16_bf16(Af[2][s], Bf[2][s], aq, 0, 0, 0);
      }
      // prefetch next tile's inputs while MFMA/stores fly
      {
        int tn = t + (int)gridDim.x;
        size_t ptn = (size_t)(tn < nt ? tn : t) * 64 + pl;
        xx = X[ptn]; yy = Y[ptn]; vv = V[ptn]; v0v = V0[ptn];
      }
      bar_lgkm();  // barC: all rt0 store-pass reads of outt done
#pragma unroll
      for (int i = 0; i < 16; ++i) {
        int rl = (i & 3) + 8 * (i >> 2) + 4 * hi;
        outt[rl][col] = ar[i] * ag[i] + aq[i];
      }
    }
    bar_lgkm();  // barD: outt(rt1) complete

    // store pass rt1; next tile's E may start right after (enc reads all pre-barC)
    {
      const float* src = &outt[0][0];
      size_t base = (size_t)(t * 64 + 32) * 256;
#pragma unroll
      for (int it = 0; it < 4; ++it) {
        int idx = it * 2048 + tid * 4;
        f32x4 v = *(const f32x4*)(src + idx);
        __builtin_nontemporal_store(v, (f32x4*)(Out + base + idx));
      }
    }
  }
}

extern "C" void kernel_launch(void* const* d_in, const int* in_sizes, int n_in,
                              void* d_out, int out_size, void* d_ws, size_t ws_size,
                              hipStream_t stream) {
  const float* X  = (const float*)d_in[0];
  const float* Y  = (const float*)d_in[1];
  const float* V  = (const float*)d_in[2];
  const float* V0 = (const float*)d_in[3];
  const float* Wr = (const float*)d_in[4];
  const float* Wg = (const float*)d_in[5];
  const float* Wb = (const float*)d_in[6];
  const float* Br = (const float*)d_in[7];
  const float* Bg = (const float*)d_in[8];
  const float* Bb = (const float*)d_in[9];
  float* Out = (float*)d_out;
  int n  = in_sizes[0];
  int nt = n >> 6;  // N=1e6 is divisible by 64
  // 512 blocks x 512 threads = 2 resident blocks/CU (56.5KB LDS),
  // 16 waves/CU = 4 waves/SIMD.
  qpe_kernel<<<dim3(512), dim3(512), 0, stream>>>(X, Y, V, V0, Wr, Wg, Wb,
                                                  Br, Bg, Bb, Out, nt);
}

// Round 8
// 212.763 us; speedup vs baseline: 1.7230x; 1.0250x over previous
//
#include <hip/hip_runtime.h>

// Quadratic positional encoding, fused:
//   out = (E0@Wr + br) * (E@Wg + bg) + (E*E)@Wb + bb,  E = 36-dim trig encoding
// N=1e6 points, OUT=256. Output 1.02 GB f32 -> store-BW bound (~155us at 6.8TB/s).
// R8: drop non-temporal flag on output stores. Full 128B lines are written by
// single wave-instructions, so L2 takes them without RFO and writes back
// asynchronously (like the 6.8TB/s fill kernel); nt bypassed L2 and throttled
// store issue on per-CU HBM write credits, serializing compute with drain.

typedef short bf16x8 __attribute__((ext_vector_type(8)));
typedef float f32x16 __attribute__((ext_vector_type(16)));
typedef float f32x4  __attribute__((ext_vector_type(4)));
typedef unsigned int u32x2 __attribute__((ext_vector_type(2)));

__device__ __forceinline__ unsigned short f2bf(float x) {  // setup only
  unsigned int u = __float_as_uint(x);
  return (unsigned short)((u + 0x7FFFu + ((u >> 16) & 1u)) >> 16);  // RNE
}

// pack 2 f32 -> 2 bf16 (RNE) in one instruction
__device__ __forceinline__ unsigned int cvtpk(float lo, float hi) {
  unsigned int r;
  asm("v_cvt_pk_bf16_f32 %0, %1, %2" : "=v"(r) : "v"(lo), "v"(hi));
  return r;
}

// a in radians; v_sin/v_cos take revolutions, reduce with fract first
__device__ __forceinline__ void fsincos(float a, float* s, float* c) {
  float r = a * 0.15915494309189535f;
  r = r - floorf(r);
  *s = __builtin_amdgcn_sinf(r);
  *c = __builtin_amdgcn_cosf(r);
}

// Barrier that only drains LDS ops: global stores keep flying. All
// inter-wave dependencies in the tile loop are through LDS (enc/outt).
__device__ __forceinline__ void bar_lgkm() {
  asm volatile("s_waitcnt lgkmcnt(0)" ::: "memory");
  __builtin_amdgcn_s_barrier();
  asm volatile("" ::: "memory");
}

// Reordered K layout (k'):
//   k' 0..31  : freq f = k'>>2, comp {sin px, cos px, sin py, cos py} (orig k = k'+4)
//   k' 32..35 : header {x, y, sin base, cos base} (orig k = 0..3)
//   k' 36     : constant 1.0; B row 36 = bias  -> epilogue is one fma
//   k' 37..47 : zero pad
__global__ __launch_bounds__(512, 4) void qpe_kernel(
    const float* __restrict__ X, const float* __restrict__ Y,
    const float* __restrict__ V, const float* __restrict__ V0,
    const float* __restrict__ Wr, const float* __restrict__ Wg,
    const float* __restrict__ Wb, const float* __restrict__ Br,
    const float* __restrict__ Bg, const float* __restrict__ Bb,
    float* __restrict__ Out, int nt)
{
  __shared__ __align__(16) unsigned short enc[3][64][64];  // 24.5 KB, rows 128B, XOR-swizzled
  __shared__ __align__(16) float outt[32][256];            // 32 KB output staging (one rt tile)

  const int tid  = threadIdx.x;
  const int lane = tid & 63;
  const int wid  = tid >> 6;   // wave 0..7 -> col block wid*32
  const int hi   = lane >> 5;  // 0/1
  const int ln   = lane & 31;

  // ---- zero entire enc LDS once (pad rows stay zero forever) ----
  {
    bf16x8 z = {0,0,0,0,0,0,0,0};
    bf16x8* pz = (bf16x8*)(&enc[0][0][0]);
#pragma unroll
    for (int i = 0; i < 3; ++i) pz[tid + 512 * i] = z;
  }
  __syncthreads();
  // ---- k'=36 constant-1.0 row (swizzled address, set once) ----
  if (tid < 192) {
    int m = tid >> 6, p = tid & 63;
    int swz = (p & 7) << 4;
    // chunk 4 (k'32..39) lives at byte (64^swz); k'36,37 are its bytes 8..11
    *(unsigned int*)((char*)&enc[m][p][0] + ((64 ^ swz) + 8)) = 0x00003F80u;  // {1.0bf, 0}
  }

  // ---- resident B fragments (3 mats x 3 K-steps, 32 cols/wave) ----
  bf16x8 Bf[3][3];
  {
    const float* const Wm[3] = {Wr, Wg, Wb};
    const float* const Bs[3] = {Br, Bg, Bb};
    int col = wid * 32 + ln;
#pragma unroll
    for (int m = 0; m < 3; ++m) {
#pragma unroll
      for (int s = 0; s < 3; ++s) {
        bf16x8 f;
#pragma unroll
        for (int j = 0; j < 8; ++j) {
          int kp = s * 16 + hi * 8 + j;
          float val = 0.0f;
          if (kp < 32)       val = Wm[m][(kp + 4) * 256 + col];  // freq rows
          else if (kp < 36)  val = Wm[m][(kp - 32) * 256 + col]; // x,y,sinb,cosb
          else if (kp == 36) val = Bs[m][col];                   // bias row
          f[j] = (short)f2bf(val);
        }
        Bf[m][s] = f;
      }
    }
  }
  __syncthreads();

  const float TPF = 62.831853071795864f;  // 2*pi*10
  const int   pl = tid >> 3;              // point-local 0..63
  const int   qq = tid & 7;               // freq 0..7
  const float sc = __int_as_float((124 + qq) << 23);  // 2^(qq-3)

  // input prefetch registers (consumed at top of tile, refilled mid-tile)
  size_t pt0 = (size_t)blockIdx.x * 64 + pl;
  float xx = X[pt0], yy = Y[pt0], vv = V[pt0], v0v = V0[pt0];

  for (int t = blockIdx.x; t < nt; t += gridDim.x) {
    // ======== E phase: 64 points x 8 threads (1 freq each) ========
    {
      float wn  = TPF / vv;
      float wn0 = TPF / v0v;
      float xw0 = xx * wn0, yw0 = yy * wn0, xw = xx * wn, yw = yy * wn;
      float sx0, cx0, sy0, cy0, sx, cx, sy, cy;
      fsincos(xw0 * sc, &sx0, &cx0);
      fsincos(yw0 * sc, &sy0, &cy0);
      fsincos(xw  * sc, &sx,  &cx);
      fsincos(yw  * sc, &sy,  &cy);
      int swz = (pl & 7) << 4;
      int off = (8 * qq) ^ swz;
      u32x2 w0; w0[0] = cvtpk(sx0, cx0);         w0[1] = cvtpk(sy0, cy0);
      u32x2 w1; w1[0] = cvtpk(sx, cx);           w1[1] = cvtpk(sy, cy);
      u32x2 w2; w2[0] = cvtpk(sx * sx, cx * cx); w2[1] = cvtpk(sy * sy, cy * cy);
      *(u32x2*)((char*)&enc[0][pl][0] + off) = w0;
      *(u32x2*)((char*)&enc[1][pl][0] + off) = w1;
      *(u32x2*)((char*)&enc[2][pl][0] + off) = w2;
      if (qq == 0) {
        float s0, c0, s1, c1;
        fsincos(xw0 * 0.0625f, &s0, &c0);
        fsincos(xw  * 0.0625f, &s1, &c1);
        u32x2 h0; h0[0] = cvtpk(xx, yy);           h0[1] = cvtpk(s0, c0);
        u32x2 h1; h1[0] = cvtpk(xx, yy);           h1[1] = cvtpk(s1, c1);
        u32x2 h2; h2[0] = cvtpk(xx * xx, yy * yy); h2[1] = cvtpk(s1 * s1, c1 * c1);
        int hoff = 64 ^ swz;   // chunk 4 bytes 0..7 = k'32..35
        *(u32x2*)((char*)&enc[0][pl][0] + hoff) = h0;
        *(u32x2*)((char*)&enc[1][pl][0] + hoff) = h1;
        *(u32x2*)((char*)&enc[2][pl][0] + hoff) = h2;
      }
    }
    bar_lgkm();  // barA: enc ready; prev-tile store1 reads of outt also pre-date this

    // ======== rt0: MFMA + 1-fma epilogue into outt ========
    const int col = wid * 32 + ln;
    {
      bf16x8 Af[3][3];
      int swz2 = (ln & 7) << 4;
#pragma unroll
      for (int m = 0; m < 3; ++m)
#pragma unroll
        for (int s = 0; s < 3; ++s)
          Af[m][s] = *(const bf16x8*)((const char*)&enc[m][ln][0] +
                                      ((s * 32 + hi * 16) ^ swz2));
      f32x16 ar, ag, aq;
#pragma unroll
      for (int i = 0; i < 16; ++i) { ar[i] = 0.f; ag[i] = 0.f; aq[i] = 0.f; }
#pragma unroll
      for (int s = 0; s < 3; ++s) {
        ar = __builtin_amdgcn_mfma_f32_32x32x16_bf16(Af[0][s], Bf[0][s], ar, 0, 0, 0);
        ag = __builtin_amdgcn_mfma_f32_32x32x16_bf16(Af[1][s], Bf[1][s], ag, 0, 0, 0);
        aq = __builtin_amdgcn_mfma_f32_32x32x16_bf16(Af[2][s], Bf[2][s], aq, 0, 0, 0);
      }
#pragma unroll
      for (int i = 0; i < 16; ++i) {
        int rl = (i & 3) + 8 * (i >> 2) + 4 * hi;
        outt[rl][col] = ar[i] * ag[i] + aq[i];
      }
    }
    bar_lgkm();  // barB: outt(rt0) complete

    // store pass rt0 (plain stores -> L2 write-back) + rt1 A-loads/MFMA overlap
    {
      const float* src = &outt[0][0];
      size_t base = (size_t)(t * 64) * 256;
#pragma unroll
      for (int it = 0; it < 4; ++it) {
        int idx = it * 2048 + tid * 4;
        f32x4 v = *(const f32x4*)(src + idx);
        *(f32x4*)(Out + base + idx) = v;
      }
    }
    {
      bf16x8 Af[3][3];
      int p = 32 + ln;
      int swz2 = (p & 7) << 4;
#pragma unroll
      for (int m = 0; m < 3; ++m)
#pragma unroll
        for (int s = 0; s < 3; ++s)
          Af[m][s] = *(const bf16x8*)((const char*)&enc[m][p][0] +
                                      ((s * 32 + hi * 16) ^ swz2));
      f32x16 ar, ag, aq;
#pragma unroll
      for (int i = 0; i < 16; ++i) { ar[i] = 0.f; ag[i] = 0.f; aq[i] = 0.f; }
#pragma unroll
      for (int s = 0; s < 3; ++s) {
        ar = __builtin_amdgcn_mfma_f32_32x32x16_bf16(Af[0][s], Bf[0][s], ar, 0, 0, 0);
        ag = __builtin_amdgcn_mfma_f32_32x32x16_bf16(Af[1][s], Bf[1][s], ag, 0, 0, 0);
        aq = __builtin_amdgcn_mfma_f32_32x32x16_bf16(Af[2][s], Bf[2][s], aq, 0, 0, 0);
      }
      // prefetch next tile's inputs while MFMA/stores fly
      {
        int tn = t + (int)gridDim.x;
        size_t ptn = (size_t)(tn < nt ? tn : t) * 64 + pl;
        xx = X[ptn]; yy = Y[ptn]; vv = V[ptn]; v0v = V0[ptn];
      }
      bar_lgkm();  // barC: all rt0 store-pass reads of outt done
#pragma unroll
      for (int i = 0; i < 16; ++i) {
        int rl = (i & 3) + 8 * (i >> 2) + 4 * hi;
        outt[rl][col] = ar[i] * ag[i] + aq[i];
      }
    }
    bar_lgkm();  // barD: outt(rt1) complete

    // store pass rt1; next tile's E may start right after (enc reads all pre-barC)
    {
      const float* src = &outt[0][0];
      size_t base = (size_t)(t * 64 + 32) * 256;
#pragma unroll
      for (int it = 0; it < 4; ++it) {
        int idx = it * 2048 + tid * 4;
        f32x4 v = *(const f32x4*)(src + idx);
        *(f32x4*)(Out + base + idx) = v;
      }
    }
  }
}

extern "C" void kernel_launch(void* const* d_in, const int* in_sizes, int n_in,
                              void* d_out, int out_size, void* d_ws, size_t ws_size,
                              hipStream_t stream) {
  const float* X  = (const float*)d_in[0];
  const float* Y  = (const float*)d_in[1];
  const float* V  = (const float*)d_in[2];
  const float* V0 = (const float*)d_in[3];
  const float* Wr = (const float*)d_in[4];
  const float* Wg = (const float*)d_in[5];
  const float* Wb = (const float*)d_in[6];
  const float* Br = (const float*)d_in[7];
  const float* Bg = (const float*)d_in[8];
  const float* Bb = (const float*)d_in[9];
  float* Out = (float*)d_out;
  int n  = in_sizes[0];
  int nt = n >> 6;  // N=1e6 is divisible by 64
  // 512 blocks x 512 threads = 2 resident blocks/CU (56.5KB LDS, 128 VGPR),
  // 16 waves/CU = 4 waves/SIMD.
  qpe_kernel<<<dim3(512), dim3(512), 0, stream>>>(X, Y, V, V0, Wr, Wg, Wb,
                                                  Br, Bg, Bb, Out, nt);
}